// Round 4
// baseline (710.757 us; speedup 1.0000x reference)
//
#include <hip/hip_runtime.h>

typedef unsigned int uint_t;

// ---------------- compile-time PGA G(3,0,1) tables ----------------
// blade index order matches reference _BLADES; mask bit e = basis vector e present
constexpr int MASK_OF_IDX[16] = {0,1,2,4,8,3,5,9,6,10,12,7,11,13,14,15};
constexpr int IDX_OF_MASK[16] = {0,1,2,5,3,6,8,11,4,7,9,12,10,13,14,15};

constexpr int popc4(int v){ int c=0; for(int b=0;b<4;++b) c += (v>>b)&1; return c; }
// (-1)^{#inversions to interleave sorted blade a with sorted blade b}
constexpr int reorder_sign(int a,int b){ int s=0; for(int j=0;j<4;++j) if((b>>j)&1) s += popc4(a>>(j+1)); return (s&1)?-1:1; }
// dual sign: perm_sign(b + comp(b))
constexpr int dsign_mask(int m){ int comp=(~m)&15; int s=0; for(int j=0;j<4;++j) if((comp>>j)&1) s += popc4(m>>(j+1)); return (s&1)?-1:1; }

struct Tab { int n; int e[256]; };
constexpr Tab build_gp(){
  Tab t{}; t.n=0;
  for(int i=0;i<16;++i) for(int j=0;j<16;++j){
    int a=MASK_OF_IDX[i], b=MASK_OF_IDX[j];
    if(a&b&1) continue;                      // e0^2 = 0
    int k=IDX_OF_MASK[a^b];
    int s=reorder_sign(a,b);
    t.e[t.n++] = i | (j<<4) | (k<<8) | ((s<0)?(1<<12):0);
  }
  return t;
}
constexpr Tab build_jc(){
  Tab t{}; t.n=0;
  for(int i=0;i<16;++i) for(int j=0;j<16;++j){
    int a=MASK_OF_IDX[i], b=MASK_OF_IDX[j];
    int da=(~a)&15, db=(~b)&15;
    if(da&db) continue;
    int m=da|db, km=(~m)&15;
    int k=IDX_OF_MASK[km];
    int s=reorder_sign(da,db)*dsign_mask(a)*dsign_mask(b)*dsign_mask(km);
    t.e[t.n++] = i | (j<<4) | (k<<8) | ((s<0)?(1<<12):0);
  }
  return t;
}
constexpr Tab GPT = build_gp();
constexpr Tab JCT = build_jc();
static_assert(GPT.n==192, "gp nnz");
static_assert(JCT.n==81,  "jc nnz");

// 16 fp32 from GLOBAL (16B-aligned) -> registers
__device__ __forceinline__ void ld16(const float* p, float* xv){
  const float4* q = (const float4*)p;
  float4 a = q[0], b = q[1], c = q[2], d = q[3];
  xv[0]=a.x; xv[1]=a.y; xv[2]=a.z; xv[3]=a.w;
  xv[4]=b.x; xv[5]=b.y; xv[6]=b.z; xv[7]=b.w;
  xv[8]=c.x; xv[9]=c.y; xv[10]=c.z; xv[11]=c.w;
  xv[12]=d.x; xv[13]=d.y; xv[14]=d.z; xv[15]=d.w;
}
// 16 fp32 -> GLOBAL (16B-aligned)
__device__ __forceinline__ void st16(float* p, const float* v){
  float4* q = (float4*)p;
  q[0] = make_float4(v[0],v[1],v[2],v[3]);
  q[1] = make_float4(v[4],v[5],v[6],v[7]);
  q[2] = make_float4(v[8],v[9],v[10],v[11]);
  q[3] = make_float4(v[12],v[13],v[14],v[15]);
}

// one equi_linear accumulation step: acc[k] += w[grade(k)]*x[k] + e0-map terms
__device__ __forceinline__ void eqstep(float* acc, const float* xv, const float* w){
  constexpr int G[16] = {0,1,1,1,1,2,2,2,2,2,2,3,3,3,3,4};
#pragma unroll
  for (int k=0;k<16;++k) acc[k] += w[G[k]]*xv[k];
  // blades containing e0 get 'left-multiply-by-e0' contribution from the e0-free partner
  acc[1]  += w[5]*xv[0];
  acc[5]  += w[6]*xv[2];
  acc[6]  += w[6]*xv[3];
  acc[7]  += w[6]*xv[4];
  acc[11] += w[7]*xv[8];
  acc[12] += w[7]*xv[9];
  acc[13] += w[7]*xv[10];
  acc[15] += w[8]*xv[14];
}

#define TT   16     // tokens per workgroup
#define NTHR 256

__global__ __launch_bounds__(NTHR) void gatr_fused_kernel(
    const float* __restrict__ xg, const float* __restrict__ refg,
    const float* __restrict__ wbilg, const float* __restrict__ bbilg,
    const float* __restrict__ woutg, const float* __restrict__ boutg,
    float* __restrict__ outg)
{
  // y = concat(gp, join): [32 channels][16 tokens][17 floats (16 + 1 pad)]
  __shared__ float YSf[32 * TT * 17];          // 34,816 B

  const int tid  = threadIdx.x;
  const int tok0 = blockIdx.x * TT;
  const int t = tid & (TT-1);      // token in tile
  const int c = tid >> 4;          // intermediate channel 0..15

  // ---- phase 1+2: equi_linear(bilinear) + GP/JC, all in registers ----
  {
    float A0[16], A1[16], A2[16], A3[16];   // lg, rg, lj, rj for channel c
#pragma unroll
    for (int k=0;k<16;++k){ A0[k]=0.f; A1[k]=0.f; A2[k]=0.f; A3[k]=0.f; }

    const float* xrow = xg + ((size_t)(tok0 + t))*512;
    for (int i=0;i<32;++i){
      float xv[16];
      ld16(xrow + i*16, xv);
      eqstep(A0, xv, wbilg + ((c     )*32 + i)*9);
      eqstep(A1, xv, wbilg + ((c + 16)*32 + i)*9);
      eqstep(A2, xv, wbilg + ((c + 32)*32 + i)*9);
      eqstep(A3, xv, wbilg + ((c + 48)*32 + i)*9);
    }
    A0[0] += bbilg[c];
    A1[0] += bbilg[c + 16];
    A2[0] += bbilg[c + 32];
    A3[0] += bbilg[c + 48];

    float gp[16], jn[16];
#pragma unroll
    for (int k=0;k<16;++k){ gp[k]=0.f; jn[k]=0.f; }
#pragma unroll
    for (int e=0;e<192;++e){
      const int p = GPT.e[e];
      float v = A0[p & 15] * A1[(p >> 4) & 15];
      if (p & (1<<12)) gp[(p >> 8) & 15] -= v; else gp[(p >> 8) & 15] += v;
    }
#pragma unroll
    for (int e=0;e<81;++e){
      const int p = JCT.e[e];
      float v = A2[p & 15] * A3[(p >> 4) & 15];
      if (p & (1<<12)) jn[(p >> 8) & 15] -= v; else jn[(p >> 8) & 15] += v;
    }
    const float refv = refg[((size_t)(tok0 + t))*16 + 15];
#pragma unroll
    for (int k=0;k<16;++k) jn[k] *= refv;

#pragma unroll
    for (int k=0;k<16;++k){
      YSf[((c     )*TT + t)*17 + k] = gp[k];
      YSf[((c + 16)*TT + t)*17 + k] = jn[k];
    }
  }
  __syncthreads();

  // ---- phase 3: equi_linear(out) ----
  {
    const int g = c;                 // out channels g and g+16
    float B0a[16], B1a[16];
#pragma unroll
    for (int k=0;k<16;++k){ B0a[k]=0.f; B1a[k]=0.f; }

    for (int cin=0; cin<32; ++cin){
      float yv[16];
#pragma unroll
      for (int k=0;k<16;++k) yv[k] = YSf[(cin*TT + t)*17 + k];
      eqstep(B0a, yv, woutg + ((g     )*32 + cin)*9);
      eqstep(B1a, yv, woutg + ((g + 16)*32 + cin)*9);
    }
    B0a[0] += boutg[g];
    B1a[0] += boutg[g + 16];

    float* orow = outg + ((size_t)(tok0 + t))*512;
    st16(orow + (g     )*16, B0a);
    st16(orow + (g + 16)*16, B1a);
  }
}

extern "C" void kernel_launch(void* const* d_in, const int* in_sizes, int n_in,
                              void* d_out, int out_size, void* d_ws, size_t ws_size,
                              hipStream_t stream) {
  const float* x    = (const float*)d_in[0];
  const float* ref  = (const float*)d_in[1];
  const float* wbil = (const float*)d_in[2];
  const float* bbil = (const float*)d_in[3];
  const float* wout = (const float*)d_in[4];
  const float* bout = (const float*)d_in[5];
  float* out = (float*)d_out;

  const int ntok = in_sizes[0] / 512;   // 8*8192 = 65536 tokens
  const int grid = ntok / TT;           // 4096 workgroups
  hipLaunchKernelGGL(gatr_fused_kernel, dim3(grid), dim3(NTHR), 0, stream,
                     x, ref, wbil, bbil, wout, bout, out);
}